// Round 2
// baseline (81.537 us; speedup 1.0000x reference)
//
#include <hip/hip_runtime.h>

// x: (32, 3, 1024, 1024) f32, l: (32,2) i32
// out = [ full: 32*3*1024*1024 f32 , patch: 32*3*128*128 f32 ]
//
// window rows = l0 - 193 + i (i in [0,128)), cols = l1 - 193 + j (j in [0,128))
// patch[b,c,i,j] = valid ? x[b,c,row,col] : 0
// full = x masked to the valid window, 0 elsewhere.

#define FULL_ELEMS  (32L * 3 * 1024 * 1024)   // 100663296
#define PATCH_ELEMS (32L * 3 * 128 * 128)     // 1572864

// full: one wave handles one full image row (1024 floats = 256 float4, 64 lanes x 4).
// 4 waves/block -> 4 rows/block. Total rows = 32*3*1024 = 98304 -> 24576 blocks.
#define FULL_BLOCKS 24576
// patch: 393216 float4s, 1024 float4s per block (256 thr x 4) -> 384 blocks.
#define PATCH_BLOCKS 384

__global__ __launch_bounds__(256) void retina_fused(const float* __restrict__ x,
                                                    const int* __restrict__ l,
                                                    float* __restrict__ full,
                                                    float* __restrict__ patch) {
    int bid = blockIdx.x;
    if (bid < FULL_BLOCKS) {
        int wave = threadIdx.x >> 6;
        int lane = threadIdx.x & 63;
        int row  = (bid << 2) + wave;        // global row in [0, 98304)
        int r    = row & 1023;               // row within image
        int bc   = row >> 10;                // (b,c) in [0,96)
        int b    = bc / 3;                   // magic-mul, wave-uniform
        int l0 = l[2 * b];
        int l1 = l[2 * b + 1];
        int i  = r - (l0 - 193);             // patch row index (wave-uniform)
        const float4* xrow = (const float4*)(x    + ((long)row << 10));
        float4*       frow = (float4*)      (full + ((long)row << 10));
        if ((unsigned)i < 128u) {
            int jbase0 = -(l1 - 193);        // j of element w=0
#pragma unroll
            for (int k = 0; k < 4; ++k) {
                int w4 = lane + (k << 6);
                int jb = jbase0 + (w4 << 2); // j of this float4's first elem
                float4 o = make_float4(0.f, 0.f, 0.f, 0.f);
                if (jb >= -3 && jb < 128) {  // some elem inside col window
                    float4 v = xrow[w4];
                    o.x = ((unsigned)(jb + 0) < 128u) ? v.x : 0.f;
                    o.y = ((unsigned)(jb + 1) < 128u) ? v.y : 0.f;
                    o.z = ((unsigned)(jb + 2) < 128u) ? v.z : 0.f;
                    o.w = ((unsigned)(jb + 3) < 128u) ? v.w : 0.f;
                }
                frow[w4] = o;
            }
        } else {
            // wave-uniform zero path: 4 pure dwordx4 stores, no loads
            float4 z = make_float4(0.f, 0.f, 0.f, 0.f);
#pragma unroll
            for (int k = 0; k < 4; ++k) frow[lane + (k << 6)] = z;
        }
    } else {
        // patch blocks
        int pb = bid - FULL_BLOCKS;
#pragma unroll
        for (int k = 0; k < 4; ++k) {
            int p4 = (pb << 10) + (k << 8) + threadIdx.x;  // float4 index in patch
            int j4 = p4 & 31;                  // col float4 (128/4)
            int i  = (p4 >> 5) & 127;          // patch row
            int bc = p4 >> 12;                 // (b,c) in [0,96)
            int b  = bc / 3;
            int l0 = l[2 * b];
            int l1 = l[2 * b + 1];
            int r  = l0 - 193 + i;
            float o[4] = {0.f, 0.f, 0.f, 0.f};
            if ((unsigned)r < 1024u) {
                const float* xrow = x + (((long)bc << 10) + r) * 1024;
                int wbase = l1 - 193 + (j4 << 2);
#pragma unroll
                for (int e = 0; e < 4; ++e) {
                    int w = wbase + e;
                    if ((unsigned)w < 1024u) o[e] = xrow[w];
                }
            }
            *(float4*)(patch + ((long)p4 << 2)) = make_float4(o[0], o[1], o[2], o[3]);
        }
    }
}

extern "C" void kernel_launch(void* const* d_in, const int* in_sizes, int n_in,
                              void* d_out, int out_size, void* d_ws, size_t ws_size,
                              hipStream_t stream) {
    const float* x = (const float*)d_in[0];
    const int*   l = (const int*)d_in[1];
    float* full  = (float*)d_out;
    float* patch = full + FULL_ELEMS;
    retina_fused<<<FULL_BLOCKS + PATCH_BLOCKS, 256, 0, stream>>>(x, l, full, patch);
}

// Round 3
// 70.626 us; speedup vs baseline: 1.1545x; 1.1545x over previous
//
#include <hip/hip_runtime.h>

// x: (32, 3, 1024, 1024) f32, l: (32,2) i32
// out = [ full: 32*3*1024*1024 f32 , patch: 32*3*128*128 f32 ]
//
// window rows = l0 - 193 + i (i in [0,128)), cols = l1 - 193 + j (j in [0,128))
// patch[b,c,i,j] = valid ? x[b,c,row,col] : 0
// full = x masked to the valid window, 0 elsewhere.

#define FULL_ELEMS  (32L * 3 * 1024 * 1024)   // 100663296

// full: 1 block = 1 image row (1024 floats = 256 float4s, threadIdx.x = w4).
// All window math is block-uniform -> scalar regs. 98304 row-blocks.
#define FULL_BLOCKS 98304
// patch: 393216 float4s, one per thread -> 1536 blocks.
#define PATCH_BLOCKS 1536

__global__ __launch_bounds__(256) void retina_fused(const float* __restrict__ x,
                                                    const int* __restrict__ l,
                                                    float* __restrict__ full,
                                                    float* __restrict__ patch) {
    int bid = blockIdx.x;
    if (bid < FULL_BLOCKS) {
        // ---- full: one row per block, all control scalar ----
        int r  = bid & 1023;                 // row within image   (scalar)
        int bc = bid >> 10;                  // (b,c) in [0,96)    (scalar)
        int b  = bc / 3;                     // scalar magic-mul
        int l0 = l[2 * b];                   // s_load (K$)
        int l1 = l[2 * b + 1];
        int i  = r - (l0 - 193);             // patch row idx      (scalar)
        float4* frow = (float4*)(full + ((long)bid << 10));
        int w4 = threadIdx.x;
        if ((unsigned)i >= 128u) {
            // out-of-window row: pure zero store, ~6 instrs/thread
            frow[w4] = make_float4(0.f, 0.f, 0.f, 0.f);
        } else {
            const float4* xrow = (const float4*)(x + ((long)bid << 10));
            int jb = (w4 << 2) - (l1 - 193); // patch col of elem 0 (per-thread)
            float4 o = make_float4(0.f, 0.f, 0.f, 0.f);
            if (jb >= -3 && jb < 128) {      // float4 overlaps col window
                float4 v = xrow[w4];
                o.x = ((unsigned)(jb + 0) < 128u) ? v.x : 0.f;
                o.y = ((unsigned)(jb + 1) < 128u) ? v.y : 0.f;
                o.z = ((unsigned)(jb + 2) < 128u) ? v.z : 0.f;
                o.w = ((unsigned)(jb + 3) < 128u) ? v.w : 0.f;
            }
            frow[w4] = o;
        }
    } else {
        // ---- patch: one float4 per thread (identical to the R0-verified logic) ----
        int tid = (bid - FULL_BLOCKS) * 256 + (int)threadIdx.x;
        int j4 = tid & 31;                   // col float4 (128/4)
        int i  = (tid >> 5) & 127;           // patch row
        int bc = tid >> 12;                  // (b,c) in [0,96)
        int b  = bc / 3;
        int l0 = l[2 * b];
        int l1 = l[2 * b + 1];
        int r  = l0 - 193 + i;
        float o[4] = {0.f, 0.f, 0.f, 0.f};
        if ((unsigned)r < 1024u) {
            const float* xrow = x + (((long)bc << 10) + r) * 1024;
            int wbase = l1 - 193 + (j4 << 2);
#pragma unroll
            for (int e = 0; e < 4; ++e) {
                int w = wbase + e;
                if ((unsigned)w < 1024u) o[e] = xrow[w];
            }
        }
        *(float4*)(patch + ((long)tid << 2)) = make_float4(o[0], o[1], o[2], o[3]);
    }
}

extern "C" void kernel_launch(void* const* d_in, const int* in_sizes, int n_in,
                              void* d_out, int out_size, void* d_ws, size_t ws_size,
                              hipStream_t stream) {
    const float* x = (const float*)d_in[0];
    const int*   l = (const int*)d_in[1];
    float* full  = (float*)d_out;
    float* patch = full + FULL_ELEMS;
    retina_fused<<<FULL_BLOCKS + PATCH_BLOCKS, 256, 0, stream>>>(x, l, full, patch);
}